// Round 1
// baseline (2762.779 us; speedup 1.0000x reference)
//
#include <hip/hip_runtime.h>
#include <hip/hip_bf16.h>
#include <stdint.h>

#define T_STEPS 200
#define BATCH   256
#define NS      256   // states S
#define NA      16    // actions A
#define DOBS    128
#define DCTL    16
#define LOG2PI  1.8378770664093453f
#define EPS_F   1e-6f

typedef float f32x4 __attribute__((ext_vector_type(4)));
typedef short s16x8 __attribute__((ext_vector_type(8)));

static __device__ __forceinline__ unsigned short f2bf(float f) {
    union { float f; unsigned u; } v; v.f = f;
    unsigned u = v.u;
    u += 0x7fffu + ((u >> 16) & 1u);   // RNE
    return (unsigned short)(u >> 16);
}

// ---- prep: obs weights  W=(-0.5*iv || mu*iv) stored transposed [256 d'][256 s], C[s]
__global__ __launch_bounds__(128) void k_prep_obs(const float* __restrict__ obs_mu,
                                                  const float* __restrict__ obs_lv,
                                                  float* __restrict__ WT,
                                                  float* __restrict__ Cs) {
    int s = blockIdx.x, d = threadIdx.x;
    float lv = obs_lv[s * DOBS + d];
    float mu = obs_mu[s * DOBS + d];
    float iv = expf(-lv);
    WT[d * NS + s]          = -0.5f * iv;
    WT[(DOBS + d) * NS + s] = mu * iv;
    float part = mu * mu * iv + lv;
    for (int m = 1; m < 64; m <<= 1) part += __shfl_xor(part, m, 64);
    __shared__ float red[2];
    if ((threadIdx.x & 63) == 0) red[threadIdx.x >> 6] = part;
    __syncthreads();
    if (threadIdx.x == 0) Cs[s] = -0.5f * (red[0] + red[1] + DOBS * LOG2PI);
}

// ---- prep: ctl weights
__global__ __launch_bounds__(256) void k_prep_ctl(const float* __restrict__ cmu,
                                                  const float* __restrict__ clv,
                                                  float* __restrict__ cw1,
                                                  float* __restrict__ cw2,
                                                  float* __restrict__ cc) {
    int t = threadIdx.x;           // (a,d) pairs: a = t>>4, d = t&15
    int a = t >> 4, d = t & 15;
    float lv = clv[a * DCTL + d];
    float mu = cmu[a * DCTL + d];
    float iv = expf(-lv);
    cw1[t] = -0.5f * iv;
    cw2[t] = mu * iv;
    float part = mu * mu * iv + lv;
    for (int m = 1; m < 16; m <<= 1) part += __shfl_xor(part, m, 64);
    if (d == 0) cc[a] = -0.5f * (part + DCTL * LOG2PI);
}

// ---- prep: log_softmax(pi0)
__global__ __launch_bounds__(64) void k_prep_pi0(const float* __restrict__ pl,
                                                 float* __restrict__ lpi0) {
    int l = threadIdx.x;
    float v[4]; float m = -1e30f;
    for (int k = 0; k < 4; k++) { v[k] = pl[l + 64 * k]; m = fmaxf(m, v[k]); }
    for (int mm = 1; mm < 64; mm <<= 1) m = fmaxf(m, __shfl_xor(m, mm, 64));
    float ssum = 0.f;
    for (int k = 0; k < 4; k++) ssum += expf(v[k] - m);
    for (int mm = 1; mm < 64; mm <<= 1) ssum += __shfl_xor(ssum, mm, 64);
    float ls = logf(ssum);
    for (int k = 0; k < 4; k++) lpi0[l + 64 * k] = v[k] - m - ls;
}

// ---- prep: trans softmax, scattered into bf16 MFMA B-fragment layout.
// Column c = j*16 + a (4096 cols). Frag layout: TRf[ct=j][kk=i>>5][lane][e=i&7],
// lane = ((i>>3)&3)*16 + a  (B: col=lane&15, k-slot=(lane>>4)*8+e).
__global__ __launch_bounds__(256) void k_trans(const float* __restrict__ tl,
                                               __hip_bfloat16* __restrict__ TRf) {
    int wave = threadIdx.x >> 6, lane = threadIdx.x & 63;
    int row = blockIdx.x * 4 + wave;        // (a,i) row in [0,4096)
    int a = row >> 8, i = row & 255;
    const float* src = tl + (size_t)row * NS;
    float v[4]; float m = -1e30f;
    for (int k = 0; k < 4; k++) { v[k] = src[lane + 64 * k]; m = fmaxf(m, v[k]); }
    for (int mm = 1; mm < 64; mm <<= 1) m = fmaxf(m, __shfl_xor(m, mm, 64));
    float ssum = 0.f; float ev[4];
    for (int k = 0; k < 4; k++) { ev[k] = expf(v[k] - m); ssum += ev[k]; }
    for (int mm = 1; mm < 64; mm <<= 1) ssum += __shfl_xor(ssum, mm, 64);
    float inv = 1.f / ssum;
    int kk = i >> 5;
    int lsub = ((i >> 3) & 3) * 16 + a;
    int e = i & 7;
    for (int k = 0; k < 4; k++) {
        int j = lane + 64 * k;
        float p = ev[k] * inv;
        TRf[((size_t)(j * 8 + kk) * 64 + lsub) * 8 + e] = __float2bfloat16(p);
    }
}

// ---- obs_lp for all (t,b): GEMM [51200,256]x[256,256] f32. Block = 32 rows.
__global__ __launch_bounds__(256) void k_obslp(const float* __restrict__ x,
                                               const float* __restrict__ WT,
                                               const float* __restrict__ Cs,
                                               float* __restrict__ obs) {
    __shared__ float f[32 * 256];
    int r0 = blockIdx.x * 32;
    for (int idx = threadIdx.x; idx < 32 * DOBS; idx += 256) {
        int r = idx >> 7, d = idx & 127;
        float v = x[(size_t)(r0 + r) * DOBS + d];
        f[r * 256 + d] = v * v;
        f[r * 256 + 128 + d] = v;
    }
    __syncthreads();
    int s = threadIdx.x;
    float acc[32];
#pragma unroll
    for (int r = 0; r < 32; r++) acc[r] = 0.f;
    for (int d4 = 0; d4 < 64; d4++) {
        float w0 = WT[(d4 * 4 + 0) * NS + s];
        float w1 = WT[(d4 * 4 + 1) * NS + s];
        float w2 = WT[(d4 * 4 + 2) * NS + s];
        float w3 = WT[(d4 * 4 + 3) * NS + s];
#pragma unroll
        for (int r = 0; r < 32; r++) {
            f32x4 fv = *reinterpret_cast<const f32x4*>(&f[r * 256 + d4 * 4]);
            acc[r] += fv.x * w0 + fv.y * w1 + fv.z * w2 + fv.w * w3;
        }
    }
    float c = Cs[s];
#pragma unroll
    for (int r = 0; r < 32; r++) obs[(size_t)(r0 + r) * NS + s] = acc[r] + c;
}

// ---- ctl_lp for all (s,b,a), s in [0,199)
__global__ __launch_bounds__(256) void k_ctllp(const float* __restrict__ u,
                                               const float* __restrict__ cw1,
                                               const float* __restrict__ cw2,
                                               const float* __restrict__ cc,
                                               float* __restrict__ ctl) {
    int idx = blockIdx.x * 256 + threadIdx.x;   // (r, a)
    int r = idx >> 4, a = idx & 15;
    const float* ur = u + (size_t)r * DCTL;
    const float* w1 = cw1 + a * DCTL;
    const float* w2 = cw2 + a * DCTL;
    float acc = cc[a];
#pragma unroll
    for (int d = 0; d < 16; d++) {
        float uv = ur[d];
        acc += uv * uv * w1[d] + uv * w2[d];
    }
    ctl[idx] = acc;
}

// ---- one scan step. 256 blocks = 16 batch-tiles x 16 j-tiles, 256 threads.
__global__ __launch_bounds__(256) void k_scan(const float* __restrict__ logits_in,
                                              float* __restrict__ logits_out,
                                              const float* __restrict__ obs,
                                              const float* __restrict__ ctlp,
                                              const float* __restrict__ lpi0,
                                              const float* __restrict__ act_prior,
                                              const __hip_bfloat16* __restrict__ TRf,
                                              float* __restrict__ out_ab,
                                              float* __restrict__ out_aa,
                                              int s) {
    int bt = blockIdx.x >> 4;
    int jt = blockIdx.x & 15;
    int tid = threadIdx.x;
    int lane = tid & 63, wv = tid >> 6;
    __shared__ float p[16 * 257];     // softmaxed belief rows (padded)
    __shared__ float at[16 * 17];     // a_t rows (padded)
    int b0 = bt * 16;

    // phase 1+2: load logit rows, softmax -> p; jt==0 writes alpha_b[s]
    for (int q = 0; q < 4; q++) {
        int r = wv * 4 + q;
        int bb = b0 + r;
        float v[4]; float m = -1e30f;
        for (int k = 0; k < 4; k++) {
            int c = lane + 64 * k;
            float val = (s == 0) ? (obs[(size_t)bb * NS + c] + lpi0[c])
                                 : logits_in[(size_t)bb * NS + c];
            v[k] = val; m = fmaxf(m, val);
        }
        for (int mm = 1; mm < 64; mm <<= 1) m = fmaxf(m, __shfl_xor(m, mm, 64));
        float ssum = 0.f;
        for (int k = 0; k < 4; k++) { v[k] = expf(v[k] - m); ssum += v[k]; }
        for (int mm = 1; mm < 64; mm <<= 1) ssum += __shfl_xor(ssum, mm, 64);
        float inv = 1.f / ssum;
        for (int k = 0; k < 4; k++) {
            int c = lane + 64 * k;
            float pv = v[k] * inv;
            p[r * 257 + c] = pv;
            if (jt == 0) out_ab[((size_t)s * BATCH + bb) * NS + c] = pv;
        }
    }
    __syncthreads();

    // phase 3: a_prior = softmax(p @ act_prior); a_t = softmax(ctl_lp + log(a_prior+eps))
    {
        int r = tid >> 4, a = tid & 15;
        int bb = b0 + r;
        float g0 = 0.f, g1 = 0.f, g2 = 0.f, g3 = 0.f;
        for (int i = 0; i < NS; i += 4) {
            g0 += p[r * 257 + i + 0] * act_prior[(i + 0) * NA + a];
            g1 += p[r * 257 + i + 1] * act_prior[(i + 1) * NA + a];
            g2 += p[r * 257 + i + 2] * act_prior[(i + 2) * NA + a];
            g3 += p[r * 257 + i + 3] * act_prior[(i + 3) * NA + a];
        }
        float g = (g0 + g1) + (g2 + g3);
        float m = g;
        for (int mm = 1; mm < 16; mm <<= 1) m = fmaxf(m, __shfl_xor(m, mm, 64));
        float e = expf(g - m);
        float ssum = e;
        for (int mm = 1; mm < 16; mm <<= 1) ssum += __shfl_xor(ssum, mm, 64);
        float ap = e / ssum;
        float al = ctlp[((size_t)s * BATCH + bb) * NA + a] + logf(ap + EPS_F);
        float m2 = al;
        for (int mm = 1; mm < 16; mm <<= 1) m2 = fmaxf(m2, __shfl_xor(m2, mm, 64));
        float e2 = expf(al - m2);
        float s2 = e2;
        for (int mm = 1; mm < 16; mm <<= 1) s2 += __shfl_xor(s2, mm, 64);
        float atv = e2 / s2;
        at[r * 17 + a] = atv;
        if (jt == 0) out_aa[((size_t)s * BATCH + bb) * NA + a] = atv;
    }
    __syncthreads();

    // phase 4: A-fragments (row = lane&15 batch row, k-slot = (lane>>4)*8+e over i)
    s16x8 afr[8];
    int arow = lane & 15, kgrp = lane >> 4;
#pragma unroll
    for (int kk = 0; kk < 8; kk++) {
        s16x8 t;
#pragma unroll
        for (int e = 0; e < 8; e++) {
            float pv = p[arow * 257 + kk * 32 + kgrp * 8 + e];
            t[e] = (short)f2bf(pv);
        }
        afr[kk] = t;
    }

    // phase 5: 4 col-tiles (j values) per wave; m2 -> contract a_t -> logits_out
    for (int q = 0; q < 4; q++) {
        int ctile = wv * 4 + q;
        int ct = jt * 16 + ctile;            // global col-tile == j
        f32x4 acc = {0.f, 0.f, 0.f, 0.f};
        const s16x8* bp = reinterpret_cast<const s16x8*>(TRf) + (size_t)(ct * 8) * 64 + lane;
#pragma unroll
        for (int kk = 0; kk < 8; kk++) {
            s16x8 bfr = bp[(size_t)kk * 64];
            acc = __builtin_amdgcn_mfma_f32_16x16x32_bf16(afr[kk], bfr, acc, 0, 0, 0);
        }
        float sum[4];
#pragma unroll
        for (int r = 0; r < 4; r++) {
            float vv = acc[r] * at[(kgrp * 4 + r) * 17 + arow];   // arow == action here
            for (int mm = 1; mm < 16; mm <<= 1) vv += __shfl_xor(vv, mm, 64);
            sum[r] = vv;
        }
        if (arow == 0) {
#pragma unroll
            for (int r = 0; r < 4; r++) {
                int row_g = b0 + kgrp * 4 + r;
                float lz = logf(sum[r] + NS * EPS_F);
                float ln = obs[((size_t)(s + 1) * BATCH + row_g) * NS + ct] + lz;
                logits_out[(size_t)row_g * NS + ct] = ln;
            }
        }
    }
}

// ---- final softmax for alpha_b[T-1]
__global__ __launch_bounds__(256) void k_final(const float* __restrict__ logits_in,
                                               float* __restrict__ out_ab) {
    int bt = blockIdx.x;
    int wv = threadIdx.x >> 6, lane = threadIdx.x & 63;
    for (int q = 0; q < 4; q++) {
        int bb = bt * 16 + wv * 4 + q;
        float v[4]; float m = -1e30f;
        for (int k = 0; k < 4; k++) {
            v[k] = logits_in[(size_t)bb * NS + lane + 64 * k];
            m = fmaxf(m, v[k]);
        }
        for (int mm = 1; mm < 64; mm <<= 1) m = fmaxf(m, __shfl_xor(m, mm, 64));
        float ssum = 0.f;
        for (int k = 0; k < 4; k++) { v[k] = expf(v[k] - m); ssum += v[k]; }
        for (int mm = 1; mm < 64; mm <<= 1) ssum += __shfl_xor(ssum, mm, 64);
        float inv = 1.f / ssum;
        for (int k = 0; k < 4; k++)
            out_ab[((size_t)(T_STEPS - 1) * BATCH + bb) * NS + lane + 64 * k] = v[k] * inv;
    }
}

extern "C" void kernel_launch(void* const* d_in, const int* in_sizes, int n_in,
                              void* d_out, int out_size, void* d_ws, size_t ws_size,
                              hipStream_t stream) {
    const float* x            = (const float*)d_in[0];
    const float* u            = (const float*)d_in[1];
    const float* obs_mu       = (const float*)d_in[2];
    const float* obs_lv       = (const float*)d_in[3];
    const float* ctl_mu       = (const float*)d_in[4];
    const float* ctl_lv       = (const float*)d_in[5];
    const float* trans_logits = (const float*)d_in[6];
    const float* pi0_logits   = (const float*)d_in[7];
    const float* act_prior    = (const float*)d_in[8];

    float* out_ab = (float*)d_out;
    float* out_aa = out_ab + (size_t)T_STEPS * BATCH * NS;

    char* w = (char*)d_ws;
    size_t off = 0;
    auto alloc = [&](size_t bytes) -> void* {
        void* pp = w + off;
        off += (bytes + 255) & ~(size_t)255;
        return pp;
    };
    float* WT   = (float*)alloc((size_t)256 * 256 * 4);
    float* Cs   = (float*)alloc(256 * 4);
    float* cw1  = (float*)alloc(256 * 4);
    float* cw2  = (float*)alloc(256 * 4);
    float* cc   = (float*)alloc(16 * 4);
    float* lpi0 = (float*)alloc(256 * 4);
    __hip_bfloat16* TRf = (__hip_bfloat16*)alloc((size_t)4096 * 256 * 2);
    float* obs  = (float*)alloc((size_t)T_STEPS * BATCH * NS * 4);
    float* ctlp = (float*)alloc((size_t)(T_STEPS - 1) * BATCH * NA * 4);
    float* lgA  = (float*)alloc((size_t)BATCH * NS * 4);
    float* lgB  = (float*)alloc((size_t)BATCH * NS * 4);
    if (off > ws_size) return;   // insufficient scratch -> fail loudly (poisoned output)

    k_prep_obs<<<256, 128, 0, stream>>>(obs_mu, obs_lv, WT, Cs);
    k_prep_ctl<<<1, 256, 0, stream>>>(ctl_mu, ctl_lv, cw1, cw2, cc);
    k_prep_pi0<<<1, 64, 0, stream>>>(pi0_logits, lpi0);
    k_trans<<<1024, 256, 0, stream>>>(trans_logits, TRf);
    k_obslp<<<1600, 256, 0, stream>>>(x, WT, Cs, obs);
    k_ctllp<<<3184, 256, 0, stream>>>(u, cw1, cw2, cc, ctlp);

    for (int s = 0; s < T_STEPS - 1; s++) {
        float* lo = (s & 1) ? lgB : lgA;
        float* li = (s == 0) ? nullptr : ((s & 1) ? lgA : lgB);
        k_scan<<<256, 256, 0, stream>>>(li, lo, obs, ctlp, lpi0, act_prior, TRf,
                                        out_ab, out_aa, s);
    }
    k_final<<<16, 256, 0, stream>>>(((T_STEPS - 2) & 1) ? lgB : lgA, out_ab);
}